// Round 3
// baseline (476.499 us; speedup 1.0000x reference)
//
#include <hip/hip_runtime.h>
#include <hip/hip_bf16.h>

#define NSITES 4096
#define TOTAL_READS 131072
#define C_IN 12
#define LLEN 32
#define NF 32
#define KSZ 5
#define NCLS 3
#define RPB 16               // reads per block
#define RELEM 392            // LDS elements per read: 384 data + 8 zero pad
#define ZOFF 384             // read-relative index of the zero slot

// ws layout:
//   off : int[2][NSITES+1]  at byte 0
//   r   : float[NSITES][2*NF] at byte OFF_R
#define OFF_R (64 * 1024)

typedef __attribute__((ext_vector_type(8))) short short8v;
typedef __attribute__((ext_vector_type(4))) float float4v;

__device__ __forceinline__ unsigned short f2bf(float x) {
    union { float f; unsigned u; } v; v.f = x;
    unsigned r = (v.u + 0x7FFFu + ((v.u >> 16) & 1u)) >> 16;
    return (unsigned short)r;
}

// ---------------- K0: prefix scan of counts -> offsets ----------------
__global__ void scan_kernel(const int* __restrict__ counts, int* __restrict__ off) {
    __shared__ int part[256];
    int t = threadIdx.x;
    for (int row = 0; row < 2; ++row) {
        const int* c = counts + row * NSITES;
        int* o = off + row * (NSITES + 1);
        int local[16];
        int sum = 0;
#pragma unroll
        for (int i = 0; i < 16; ++i) { local[i] = sum; sum += c[t * 16 + i]; }
        part[t] = sum;
        __syncthreads();
        for (int d = 1; d < 256; d <<= 1) {
            int v = (t >= d) ? part[t - d] : 0;
            __syncthreads();
            part[t] += v;
            __syncthreads();
        }
        int base = (t == 0) ? 0 : part[t - 1];
#pragma unroll
        for (int i = 0; i < 16; ++i) o[t * 16 + i] = base + local[i];
        if (t == 0) o[NSITES] = TOTAL_READS;
        __syncthreads();
    }
}

// ---------------- K1: bf16-MFMA im2col conv + ragged pool ----------------
// block = 256 threads = 4 waves; block handles RPB=16 reads (4 per wave).
// Per read: y[pos,f] = sum_{k=c*5+kt} x[c,pos+kt-2] * W[f,k]  via
// 8x mfma_f32_16x16x32_bf16 (M=32 -> 2, N=32 -> 2, K=64 -> 2).
// A/B k-order uses a consistent assumed mapping (k = 8*(lane>>4)+j per
// 32-chunk) for BOTH operands -> any true hw k-permutation cancels.
__global__ __launch_bounds__(256, 2) void feat_kernel(
    const float* __restrict__ x0, const float* __restrict__ x1,
    const float* __restrict__ W0, const float* __restrict__ b0,
    const float* __restrict__ W1, const float* __restrict__ b1,
    const int* __restrict__ off, float* __restrict__ r) {

    __shared__ unsigned short xl[RPB * RELEM];   // 12544 B, bf16 bits
    __shared__ float bl[NF];
    __shared__ int   sites[RPB];

    const int blk = blockIdx.x;
    const int input = (blk >= (TOTAL_READS / RPB)) ? 1 : 0;
    const int rbase = (blk - input * (TOTAL_READS / RPB)) * RPB;
    const float* __restrict__ x  = input ? x1 : x0;
    const float* __restrict__ Wg = input ? W1 : W0;
    const float* __restrict__ bg = input ? b1 : b0;
    const int* __restrict__ orow = off + input * (NSITES + 1);

    const int t = threadIdx.x;
    const int lane = t & 63;
    const int wave = t >> 6;
    const int r16 = lane & 15;
    const int hi  = lane >> 4;

    // ---- B fragments (weights) in registers: bfrag[ni][kk]
    // lane holds col f = ni*16 + r16, k = kk*32 + hi*8 + j (0 for k>=60)
    short8v bfrag[2][2];
#pragma unroll
    for (int ni = 0; ni < 2; ++ni)
#pragma unroll
        for (int kk = 0; kk < 2; ++kk) {
            union { short8v v; unsigned short u[8]; } tmp;
#pragma unroll
            for (int j = 0; j < 8; ++j) {
                int k = kk * 32 + hi * 8 + j;
                int f = ni * 16 + r16;
                float w = (k < 60) ? Wg[f * 60 + k] : 0.f;
                tmp.u[j] = f2bf(w);
            }
            bfrag[ni][kk] = tmp.v;
        }

    // ---- A gather offsets (read-relative, element units), fixed per thread
    int aoff[2][2][8];
#pragma unroll
    for (int mi = 0; mi < 2; ++mi)
#pragma unroll
        for (int kk = 0; kk < 2; ++kk)
#pragma unroll
            for (int j = 0; j < 8; ++j) {
                int k = kk * 32 + hi * 8 + j;
                int c = k / 5, kt = k - 5 * c;
                int pos = mi * 16 + r16 + kt - 2;      // SAME pad = 2
                bool valid = (k < 60) && (pos >= 0) && (pos < 32);
                aoff[mi][kk][j] = valid ? (c * 32 + pos) : ZOFF;
            }

    // ---- stage x tile -> LDS as bf16 (16 reads x 384 floats)
    {
        const float4* xg = (const float4*)(x + (size_t)rbase * (C_IN * LLEN));
#pragma unroll
        for (int it = 0; it < 6; ++it) {
            int i = t + it * 256;          // float4 id 0..1535
            int rr = i / 96;               // read within block
            int w4 = i - rr * 96;          // ushort4 slot within read
            float4 q = xg[i];
            union { unsigned short u[4]; unsigned long long ll; } p;
            p.u[0] = f2bf(q.x); p.u[1] = f2bf(q.y);
            p.u[2] = f2bf(q.z); p.u[3] = f2bf(q.w);
            *(unsigned long long*)&xl[rr * RELEM + w4 * 4] = p.ll;
        }
        if (t < RPB * 8) {                 // zero slots
            int rr = t >> 3;
            xl[rr * RELEM + ZOFF + (t & 7)] = 0;
        }
    }
    if (t < NF) bl[t] = bg[t];
    if (t < RPB) {
        int n = rbase + t;
        int lo = 0, hq = NSITES;           // orow[lo] <= n < orow[hq]
        while (hq - lo > 1) { int mid = (lo + hq) >> 1; if (orow[mid] <= n) lo = mid; else hq = mid; }
        sites[t] = lo;
    }
    __syncthreads();

    const float bias0 = bl[r16];
    const float bias1 = bl[16 + r16];

#pragma unroll
    for (int ri = 0; ri < RPB / 4; ++ri) {
        const int rd = wave * (RPB / 4) + ri;
        const unsigned short* xr = &xl[rd * RELEM];

        float4v acc[2][2];
#pragma unroll
        for (int mi = 0; mi < 2; ++mi)
#pragma unroll
            for (int ni = 0; ni < 2; ++ni) {
                float4v z = {0.f, 0.f, 0.f, 0.f};
                acc[mi][ni] = z;
            }

#pragma unroll
        for (int kk = 0; kk < 2; ++kk) {
            short8v af[2];
#pragma unroll
            for (int mi = 0; mi < 2; ++mi) {
                union { short8v v; unsigned short u[8]; } tmp;
#pragma unroll
                for (int j = 0; j < 8; ++j) tmp.u[j] = xr[aoff[mi][kk][j]];
                af[mi] = tmp.v;
            }
#pragma unroll
            for (int mi = 0; mi < 2; ++mi)
#pragma unroll
                for (int ni = 0; ni < 2; ++ni)
                    acc[mi][ni] = __builtin_amdgcn_mfma_f32_16x16x32_bf16(
                        af[mi], bfrag[ni][kk], acc[mi][ni], 0, 0, 0);
        }

        // epilogue: relu(y + b), mean over 32 positions, ragged atomic pool.
        // C/D layout (HW-verified): col = lane&15, row = (lane>>4)*4 + reg.
        float p0 = 0.f, p1 = 0.f;
#pragma unroll
        for (int mi = 0; mi < 2; ++mi)
#pragma unroll
            for (int q = 0; q < 4; ++q) {
                p0 += fmaxf(acc[mi][0][q] + bias0, 0.f);
                p1 += fmaxf(acc[mi][1][q] + bias1, 0.f);
            }
        p0 += __shfl_xor(p0, 16, 64); p0 += __shfl_xor(p0, 32, 64);
        p1 += __shfl_xor(p1, 16, 64); p1 += __shfl_xor(p1, 32, 64);
        if (hi == 0) {
            const int s = sites[rd];
            atomicAdd(&r[s * (2 * NF) + input * NF + r16],      p0 * (1.f / 32.f));
            atomicAdd(&r[s * (2 * NF) + input * NF + 16 + r16], p1 * (1.f / 32.f));
        }
    }
}

// ---------------- K2: site combiner + softmax ----------------
__global__ void comb_kernel(const float* __restrict__ r, const float* __restrict__ W2,
                            const float* __restrict__ b2, float* __restrict__ out) {
    int s = blockIdx.x * blockDim.x + threadIdx.x;
    if (s >= NSITES) return;
    const float4* rv = (const float4*)(r + (size_t)s * (2 * NF));
    float acc[NCLS];
#pragma unroll
    for (int j = 0; j < NCLS; ++j) acc[j] = b2[j];
#pragma unroll
    for (int v = 0; v < 16; ++v) {
        float4 q = rv[v];
#pragma unroll
        for (int j = 0; j < NCLS; ++j) {
            float4 wq = ((const float4*)(W2 + j * 2 * NF))[v];
            acc[j] += q.x * wq.x + q.y * wq.y + q.z * wq.z + q.w * wq.w;
        }
    }
    float m = fmaxf(acc[0], fmaxf(acc[1], acc[2]));
    float e0 = __expf(acc[0] - m), e1 = __expf(acc[1] - m), e2 = __expf(acc[2] - m);
    float inv = 1.f / (e0 + e1 + e2);
    out[s * 3 + 0] = e0 * inv;
    out[s * 3 + 1] = e1 * inv;
    out[s * 3 + 2] = e2 * inv;
}

extern "C" void kernel_launch(void* const* d_in, const int* in_sizes, int n_in,
                              void* d_out, int out_size, void* d_ws, size_t ws_size,
                              hipStream_t stream) {
    const float* x0 = (const float*)d_in[0];
    const float* x1 = (const float*)d_in[1];
    const int* counts = (const int*)d_in[2];
    const float* W0 = (const float*)d_in[3];
    const float* b0 = (const float*)d_in[4];
    const float* W1 = (const float*)d_in[5];
    const float* b1 = (const float*)d_in[6];
    const float* W2 = (const float*)d_in[7];
    const float* b2 = (const float*)d_in[8];
    float* out = (float*)d_out;

    int* off = (int*)d_ws;
    float* r = (float*)((char*)d_ws + OFF_R);

    hipMemsetAsync(r, 0, (size_t)NSITES * 2 * NF * sizeof(float), stream);
    scan_kernel<<<1, 256, 0, stream>>>(counts, off);
    feat_kernel<<<2 * (TOTAL_READS / RPB), 256, 0, stream>>>(x0, x1, W0, b0, W1, b1, off, r);
    comb_kernel<<<(NSITES + 255) / 256, 256, 0, stream>>>(r, W2, b2, out);
}